// Round 3
// baseline (130.956 us; speedup 1.0000x reference)
//
#include <hip/hip_runtime.h>

#define N_NODES 50000
#define N_EDGES 800000
#define DFEAT 64
#define HID 128
#define NBKT 782          // buckets of 64 nodes: bkt = dst>>6
#define CAP_B 1280        // per-bucket capacity: mean 1024, sd 32 -> +8 sd
#define NSTR 66           // ns_u stride: write 2-way, frag read 2-way (free)

#define XB2 1563          // ceil(800000/512) x->bf16 blocks (512 thr)
#define WB2 8             // 4096/512 W->bf16 blocks
#define EB2 391           // edge blocks (2048 edges each)

typedef __bf16 bf16x8 __attribute__((ext_vector_type(8)));
typedef float f32x4 __attribute__((ext_vector_type(4)));

__device__ inline unsigned short f2bf(float f) {   // round-to-nearest-even
  unsigned u = __float_as_uint(f);
  return (unsigned short)((u + 0x7FFFu + ((u >> 16) & 1u)) >> 16);
}
__device__ inline float bf2f(unsigned short h) {
  return __uint_as_float(((unsigned)h) << 16);
}

// ---------- prep: bf16 cvt (x,W) + dense global bucket binning ----------
// Edge blocks: LDS histogram over 782 buckets -> one global atomicAdd per
// non-zero bucket reserves a contiguous range -> entries written densely.
__global__ __launch_bounds__(512) void k_prep(const float* __restrict__ x,
                                              const float* __restrict__ W,
                                              const int* __restrict__ ei,
                                              unsigned short* __restrict__ xb,
                                              unsigned short* __restrict__ Wb,
                                              unsigned int* __restrict__ gbuf,
                                              int* __restrict__ bcnt) {
  int bid = blockIdx.x;
  const int tid = threadIdx.x;
  if (bid < XB2) {                            // x -> bf16
    int t = bid * 512 + tid;
    if (t < N_NODES * DFEAT / 4) {
      float4 v = *(const float4*)&x[t * 4];
      ushort4 o = {f2bf(v.x), f2bf(v.y), f2bf(v.z), f2bf(v.w)};
      *(ushort4*)&xb[t * 4] = o;
    }
    return;
  }
  bid -= XB2;
  if (bid < WB2) {                            // W -> bf16
    int t = bid * 512 + tid;
    float4 v = *(const float4*)&W[t * 4];
    ushort4 o = {f2bf(v.x), f2bf(v.y), f2bf(v.z), f2bf(v.w)};
    *(ushort4*)&Wb[t * 4] = o;
    return;
  }
  bid -= WB2;                                 // edge block, 2048 edges
  __shared__ int lcnt[NBKT];
  __shared__ int lbase[NBKT];
  for (int i = tid; i < NBKT; i += 512) lcnt[i] = 0;
  __syncthreads();

  int e0 = (bid * 512 + tid) * 4;
  unsigned ent[4];
  int bkt[4], rnk[4];
  const bool act = e0 < N_EDGES;              // N_EDGES%4==0: all-or-nothing
  if (act) {
    int4 s4 = *(const int4*)&ei[e0];
    int4 d4 = *(const int4*)&ei[N_EDGES + e0];
    int ss[4] = {s4.x, s4.y, s4.z, s4.w};
    int dd[4] = {d4.x, d4.y, d4.z, d4.w};
#pragma unroll
    for (int i = 0; i < 4; ++i) {
      bkt[i] = dd[i] >> 6;                    // 64-node bucket, no division
      ent[i] = ((unsigned)(dd[i] & 63) << 16) | (unsigned)ss[i];
      rnk[i] = atomicAdd(&lcnt[bkt[i]], 1);
    }
  }
  __syncthreads();
  for (int i = tid; i < NBKT; i += 512) {     // reserve dense ranges
    int c = lcnt[i];
    lbase[i] = c ? atomicAdd(&bcnt[i], c) : 0;
  }
  __syncthreads();
  if (act) {
#pragma unroll
    for (int i = 0; i < 4; ++i) {
      int slot = lbase[bkt[i]] + rnk[i];
      if (slot < CAP_B)                       // +8-sigma guard
        gbuf[(size_t)bkt[i] * CAP_B + slot] = ent[i];
    }
  }
}

// ---------- fused: dense bucket read -> counting-sort -> gather -> MFMA fc ----------
__global__ __launch_bounds__(512) void k_gnn(const unsigned short* __restrict__ xb,
                                             const unsigned short* __restrict__ Wb,
                                             const unsigned int* __restrict__ gbuf,
                                             const int* __restrict__ bcnt,
                                             const float* __restrict__ bv,
                                             float* __restrict__ out) {
  __shared__ unsigned int sq[CAP_B];
  __shared__ unsigned int ns_u[32 * NSTR];   // [feat-pair][node], bf16x2 packed
  __shared__ int lcnt[64];
  __shared__ int lbase[65];

  const int tid = threadIdx.x;
  const int b = blockIdx.x;
  const int nb = b * 64;

  if (tid < 64) lcnt[tid] = 0;
  __syncthreads();

  int cnt = bcnt[b];
  if (cnt > CAP_B) cnt = CAP_B;
  const unsigned int* g = gbuf + (size_t)b * CAP_B;

  // counting sort by node, straight from dense global entries (<=3/thread)
  unsigned ent[3];
  int rnk[3], nloc = 0;
  for (int i = tid; i < cnt; i += 512) {
    unsigned e = g[i];
    ent[nloc] = e;
    rnk[nloc] = atomicAdd(&lcnt[e >> 16], 1);
    ++nloc;
  }
  __syncthreads();
  if (tid < 64) {
    int v = lcnt[tid];
    int inc = v;
#pragma unroll
    for (int o = 1; o < 64; o <<= 1) {
      int u = __shfl_up(inc, o);
      if (tid >= o) inc += u;
    }
    lbase[tid] = inc - v;
    if (tid == 63) lbase[64] = inc;
  }
  __syncthreads();
  for (int k = 0; k < nloc; ++k)
    sq[lbase[ent[k] >> 16] + rnk[k]] = ent[k];
  __syncthreads();

  // gather: wave w -> nodes w*8..w*8+7; lane = (entry-slot, uint2-chunk); ILP-4
  const int wave = tid >> 6;
  const int lane = tid & 63;
  const int eslot = lane >> 4;    // 4 entries per wave-load round
  const int c = lane & 15;        // uint2 chunk = features 4c..4c+3
  const uint2* xu2 = (const uint2*)xb;

#pragma unroll
  for (int i2 = 0; i2 < 8; ++i2) {
    int n = wave * 8 + i2;
    int beg = lbase[n], end = lbase[n + 1];
    float f0 = 0.f, f1 = 0.f, f2 = 0.f, f3 = 0.f;
    float g0 = 0.f, g1 = 0.f, g2 = 0.f, g3 = 0.f;
    float h0 = 0.f, h1 = 0.f, h2 = 0.f, h3 = 0.f;
    float p0 = 0.f, p1 = 0.f, p2 = 0.f, p3 = 0.f;
    int j = beg + eslot;
    for (; j + 12 < end; j += 16) {          // ILP-4: 16 entries per iter
      unsigned e0 = sq[j], e1 = sq[j + 4], e2 = sq[j + 8], e3 = sq[j + 12];
      uint2 v0 = xu2[(e0 & 0xffffu) * 16 + c];
      uint2 v1 = xu2[(e1 & 0xffffu) * 16 + c];
      uint2 v2 = xu2[(e2 & 0xffffu) * 16 + c];
      uint2 v3 = xu2[(e3 & 0xffffu) * 16 + c];
      f0 += bf2f((unsigned short)(v0.x & 0xffffu)); f1 += bf2f((unsigned short)(v0.x >> 16));
      f2 += bf2f((unsigned short)(v0.y & 0xffffu)); f3 += bf2f((unsigned short)(v0.y >> 16));
      g0 += bf2f((unsigned short)(v1.x & 0xffffu)); g1 += bf2f((unsigned short)(v1.x >> 16));
      g2 += bf2f((unsigned short)(v1.y & 0xffffu)); g3 += bf2f((unsigned short)(v1.y >> 16));
      h0 += bf2f((unsigned short)(v2.x & 0xffffu)); h1 += bf2f((unsigned short)(v2.x >> 16));
      h2 += bf2f((unsigned short)(v2.y & 0xffffu)); h3 += bf2f((unsigned short)(v2.y >> 16));
      p0 += bf2f((unsigned short)(v3.x & 0xffffu)); p1 += bf2f((unsigned short)(v3.x >> 16));
      p2 += bf2f((unsigned short)(v3.y & 0xffffu)); p3 += bf2f((unsigned short)(v3.y >> 16));
    }
    for (; j < end; j += 4) {
      unsigned e = sq[j];
      uint2 v = xu2[(e & 0xffffu) * 16 + c];
      f0 += bf2f((unsigned short)(v.x & 0xffffu)); f1 += bf2f((unsigned short)(v.x >> 16));
      f2 += bf2f((unsigned short)(v.y & 0xffffu)); f3 += bf2f((unsigned short)(v.y >> 16));
    }
    f0 += g0 + h0 + p0; f1 += g1 + h1 + p1;
    f2 += g2 + h2 + p2; f3 += g3 + h3 + p3;
    f0 += __shfl_xor(f0, 16); f0 += __shfl_xor(f0, 32);
    f1 += __shfl_xor(f1, 16); f1 += __shfl_xor(f1, 32);
    f2 += __shfl_xor(f2, 16); f2 += __shfl_xor(f2, 32);
    f3 += __shfl_xor(f3, 16); f3 += __shfl_xor(f3, 32);
    if (eslot == 0) {
      ns_u[(2 * c) * NSTR + n] = (unsigned)f2bf(f0) | ((unsigned)f2bf(f1) << 16);
      ns_u[(2 * c + 1) * NSTR + n] = (unsigned)f2bf(f2) | ((unsigned)f2bf(f3) << 16);
    }
  }
  __syncthreads();

  // fc: 8 waves. wave -> node-group g = wave&3 (16 nodes), out-group o = wave>>2 (4 nt)
  const int g2 = wave & 3;
  const int o = wave >> 2;
  const int l15 = lane & 15;
  const int quad = lane >> 4;
  const int node0 = nb + g2 * 16;

  int anode = node0 + l15;
  if (anode >= N_NODES) anode = N_NODES - 1;   // clamp; stores guarded
  const unsigned short* hx = xb + (size_t)anode * DFEAT;

  bf16x8 fa0 = *(const bf16x8*)(hx + quad * 8);        // k 0..31
  bf16x8 fa1 = *(const bf16x8*)(hx + 32 + quad * 8);   // k 32..63
  bf16x8 fa2, fa3;                                     // k 64..127 from ns_u
  {
    int m = g2 * 16 + l15;
    union { unsigned u[4]; bf16x8 v; } c2, c3;
#pragma unroll
    for (int i = 0; i < 4; ++i) {
      c2.u[i] = ns_u[(quad * 4 + i) * NSTR + m];
      c3.u[i] = ns_u[(16 + quad * 4 + i) * NSTR + m];
    }
    fa2 = c2.v;
    fa3 = c3.v;
  }

  f32x4 accr[4];
#pragma unroll
  for (int t = 0; t < 4; ++t) accr[t] = (f32x4){0.f, 0.f, 0.f, 0.f};

#pragma unroll
  for (int t = 0; t < 4; ++t) {
    int nt = o * 4 + t;
    const unsigned short* wr = Wb + (size_t)(nt * 16 + l15) * (2 * DFEAT) + quad * 8;
    bf16x8 b0 = *(const bf16x8*)(wr);
    bf16x8 b1 = *(const bf16x8*)(wr + 32);
    bf16x8 b2 = *(const bf16x8*)(wr + 64);
    bf16x8 b3 = *(const bf16x8*)(wr + 96);
    accr[t] = __builtin_amdgcn_mfma_f32_16x16x32_bf16(fa0, b0, accr[t], 0, 0, 0);
    accr[t] = __builtin_amdgcn_mfma_f32_16x16x32_bf16(fa1, b1, accr[t], 0, 0, 0);
    accr[t] = __builtin_amdgcn_mfma_f32_16x16x32_bf16(fa2, b2, accr[t], 0, 0, 0);
    accr[t] = __builtin_amdgcn_mfma_f32_16x16x32_bf16(fa3, b3, accr[t], 0, 0, 0);
  }

  // epilogue: D[m=quad*4+r][n=nt*16+l15]
#pragma unroll
  for (int t = 0; t < 4; ++t) {
    int nt = o * 4 + t;
    float bias = bv[nt * 16 + l15];
#pragma unroll
    for (int r = 0; r < 4; ++r) {
      int node = node0 + quad * 4 + r;
      if (node < N_NODES) {
        float v = accr[t][r] + bias;
        out[(size_t)node * HID + nt * 16 + l15] = v > 0.f ? v : 0.f;
      }
    }
  }
}

extern "C" void kernel_launch(void* const* d_in, const int* in_sizes, int n_in,
                              void* d_out, int out_size, void* d_ws, size_t ws_size,
                              hipStream_t stream) {
  const float* x = (const float*)d_in[0];
  const int* ei = (const int*)d_in[1];
  const float* W = (const float*)d_in[2];
  const float* b = (const float*)d_in[3];
  float* out = (float*)d_out;

  // workspace layout (~11 MB), 256B-aligned
  char* ws = (char*)d_ws;
  unsigned int* gbuf = (unsigned int*)ws;     ws += (size_t)NBKT * CAP_B * 4;
  unsigned short* xb = (unsigned short*)ws;   ws += (size_t)N_NODES * DFEAT * 2;
  unsigned short* Wb = (unsigned short*)ws;   ws += (size_t)HID * 2 * DFEAT * 2;
  int* bcnt = (int*)ws;                       ws += (size_t)NBKT * 4 + 192;

  hipMemsetAsync(bcnt, 0, NBKT * sizeof(int), stream);
  k_prep<<<XB2 + WB2 + EB2, 512, 0, stream>>>(x, W, ei, xb, Wb, gbuf, bcnt);
  k_gnn<<<NBKT, 512, 0, stream>>>(xb, Wb, gbuf, bcnt, b, out);
}

// Round 4
// 128.616 us; speedup vs baseline: 1.0182x; 1.0182x over previous
//
#include <hip/hip_runtime.h>

#define N_NODES 50000
#define N_EDGES 800000
#define DFEAT 64
#define HID 128
#define NBKT 782          // buckets of 64 nodes: bkt = dst>>6
#define CAP_B 1280        // per-bucket capacity: mean 1024, sd 32 -> +8 sd
#define NSTR 66           // ns_u stride: write 2-way, frag read 2-way (free)

#define XB2 1563          // ceil(800000/512) x->bf16 blocks (512 thr)
#define WB2 8             // 4096/512 W->bf16 blocks
#define EB2 391           // edge blocks (2048 edges each)

typedef __bf16 bf16x8 __attribute__((ext_vector_type(8)));
typedef float f32x4 __attribute__((ext_vector_type(4)));

__device__ inline unsigned short f2bf(float f) {   // round-to-nearest-even
  unsigned u = __float_as_uint(f);
  return (unsigned short)((u + 0x7FFFu + ((u >> 16) & 1u)) >> 16);
}
__device__ inline float bf2f(unsigned short h) {
  return __uint_as_float(((unsigned)h) << 16);
}

// ---------- prep: bf16 cvt (x,W) + dense global bucket binning ----------
__global__ __launch_bounds__(512) void k_prep(const float* __restrict__ x,
                                              const float* __restrict__ W,
                                              const int* __restrict__ ei,
                                              unsigned short* __restrict__ xb,
                                              unsigned short* __restrict__ Wb,
                                              unsigned int* __restrict__ gbuf,
                                              int* __restrict__ bcnt) {
  int bid = blockIdx.x;
  const int tid = threadIdx.x;
  if (bid < XB2) {                            // x -> bf16
    int t = bid * 512 + tid;
    if (t < N_NODES * DFEAT / 4) {
      float4 v = *(const float4*)&x[t * 4];
      ushort4 o = {f2bf(v.x), f2bf(v.y), f2bf(v.z), f2bf(v.w)};
      *(ushort4*)&xb[t * 4] = o;
    }
    return;
  }
  bid -= XB2;
  if (bid < WB2) {                            // W -> bf16
    int t = bid * 512 + tid;
    float4 v = *(const float4*)&W[t * 4];
    ushort4 o = {f2bf(v.x), f2bf(v.y), f2bf(v.z), f2bf(v.w)};
    *(ushort4*)&Wb[t * 4] = o;
    return;
  }
  bid -= WB2;                                 // edge block, 2048 edges
  __shared__ int lcnt[NBKT];
  __shared__ int lbase[NBKT];
  for (int i = tid; i < NBKT; i += 512) lcnt[i] = 0;
  __syncthreads();

  int e0 = (bid * 512 + tid) * 4;
  unsigned ent[4];
  int bkt[4], rnk[4];
  const bool act = e0 < N_EDGES;              // N_EDGES%4==0: all-or-nothing
  if (act) {
    int4 s4 = *(const int4*)&ei[e0];
    int4 d4 = *(const int4*)&ei[N_EDGES + e0];
    int ss[4] = {s4.x, s4.y, s4.z, s4.w};
    int dd[4] = {d4.x, d4.y, d4.z, d4.w};
#pragma unroll
    for (int i = 0; i < 4; ++i) {
      bkt[i] = dd[i] >> 6;                    // 64-node bucket, no division
      ent[i] = ((unsigned)(dd[i] & 63) << 16) | (unsigned)ss[i];
      rnk[i] = atomicAdd(&lcnt[bkt[i]], 1);
    }
  }
  __syncthreads();
  for (int i = tid; i < NBKT; i += 512) {     // reserve dense ranges
    int c = lcnt[i];
    lbase[i] = c ? atomicAdd(&bcnt[i], c) : 0;
  }
  __syncthreads();
  if (act) {
#pragma unroll
    for (int i = 0; i < 4; ++i) {
      int slot = lbase[bkt[i]] + rnk[i];
      if (slot < CAP_B)                       // +8-sigma guard
        gbuf[(size_t)bkt[i] * CAP_B + slot] = ent[i];
    }
  }
}

// ---------- fused: dense bucket read -> counting-sort -> edge-parallel gather -> MFMA fc ----------
__global__ __launch_bounds__(512) void k_gnn(const unsigned short* __restrict__ xb,
                                             const unsigned short* __restrict__ Wb,
                                             const unsigned int* __restrict__ gbuf,
                                             const int* __restrict__ bcnt,
                                             const float* __restrict__ bv,
                                             float* __restrict__ out) {
  __shared__ unsigned int sq[CAP_B];
  __shared__ unsigned int ns_u[32 * NSTR];   // [feat-pair][node], bf16x2 packed
  __shared__ int lcnt[64];
  __shared__ int lbase[65];

  const int tid = threadIdx.x;
  const int b = blockIdx.x;
  const int nb = b * 64;

  if (tid < 64) lcnt[tid] = 0;
  __syncthreads();

  int cnt = bcnt[b];
  if (cnt > CAP_B) cnt = CAP_B;
  const unsigned int* gb = gbuf + (size_t)b * CAP_B;

  // counting sort by node, straight from dense global entries (<=3/thread)
  unsigned ent[3];
  int rnk[3], nloc = 0;
  for (int i = tid; i < cnt; i += 512) {
    unsigned e = gb[i];
    ent[nloc] = e;
    rnk[nloc] = atomicAdd(&lcnt[e >> 16], 1);
    ++nloc;
  }
  __syncthreads();
  if (tid < 64) {
    int v = lcnt[tid];
    int inc = v;
#pragma unroll
    for (int o = 1; o < 64; o <<= 1) {
      int u = __shfl_up(inc, o);
      if (tid >= o) inc += u;
    }
    lbase[tid] = inc - v;
    if (tid == 63) lbase[64] = inc;
  }
  __syncthreads();
  for (int k = 0; k < nloc; ++k)
    sq[lbase[ent[k] >> 16] + rnk[k]] = ent[k];
  __syncthreads();

  // gather: edge-parallel, zero cross-lane reduces.
  // wave (8) x lane-group g3 (4) -> 2 nodes sequentially; lane c owns feats 4c..4c+3.
  // sq[j] reads are same-address broadcast (free); loop iters independent -> loads overlap.
  const int wave = tid >> 6;
  const int lane = tid & 63;
  const int g3 = lane >> 4;
  const int c = lane & 15;
  const uint2* xu2 = (const uint2*)xb;

#pragma unroll
  for (int i2 = 0; i2 < 2; ++i2) {
    int n = (wave * 4 + g3) * 2 + i2;
    int beg = lbase[n], end = lbase[n + 1];
    float A0 = 0.f, A1 = 0.f, A2 = 0.f, A3 = 0.f;
    float B0 = 0.f, B1 = 0.f, B2 = 0.f, B3 = 0.f;
    float C0 = 0.f, C1 = 0.f, C2 = 0.f, C3 = 0.f;
    float D0 = 0.f, D1 = 0.f, D2 = 0.f, D3 = 0.f;
    int j = beg;
    for (; j + 3 < end; j += 4) {            // ILP-4: 4 independent gathers in flight
      unsigned e0 = sq[j], e1 = sq[j + 1], e2 = sq[j + 2], e3 = sq[j + 3];
      uint2 v0 = xu2[(e0 & 0xffffu) * 16 + c];
      uint2 v1 = xu2[(e1 & 0xffffu) * 16 + c];
      uint2 v2 = xu2[(e2 & 0xffffu) * 16 + c];
      uint2 v3 = xu2[(e3 & 0xffffu) * 16 + c];
      A0 += bf2f((unsigned short)(v0.x & 0xffffu)); A1 += bf2f((unsigned short)(v0.x >> 16));
      A2 += bf2f((unsigned short)(v0.y & 0xffffu)); A3 += bf2f((unsigned short)(v0.y >> 16));
      B0 += bf2f((unsigned short)(v1.x & 0xffffu)); B1 += bf2f((unsigned short)(v1.x >> 16));
      B2 += bf2f((unsigned short)(v1.y & 0xffffu)); B3 += bf2f((unsigned short)(v1.y >> 16));
      C0 += bf2f((unsigned short)(v2.x & 0xffffu)); C1 += bf2f((unsigned short)(v2.x >> 16));
      C2 += bf2f((unsigned short)(v2.y & 0xffffu)); C3 += bf2f((unsigned short)(v2.y >> 16));
      D0 += bf2f((unsigned short)(v3.x & 0xffffu)); D1 += bf2f((unsigned short)(v3.x >> 16));
      D2 += bf2f((unsigned short)(v3.y & 0xffffu)); D3 += bf2f((unsigned short)(v3.y >> 16));
    }
    for (; j < end; ++j) {
      unsigned e = sq[j];
      uint2 v = xu2[(e & 0xffffu) * 16 + c];
      A0 += bf2f((unsigned short)(v.x & 0xffffu)); A1 += bf2f((unsigned short)(v.x >> 16));
      A2 += bf2f((unsigned short)(v.y & 0xffffu)); A3 += bf2f((unsigned short)(v.y >> 16));
    }
    A0 += B0 + C0 + D0; A1 += B1 + C1 + D1;
    A2 += B2 + C2 + D2; A3 += B3 + C3 + D3;
    ns_u[(2 * c) * NSTR + n] = (unsigned)f2bf(A0) | ((unsigned)f2bf(A1) << 16);
    ns_u[(2 * c + 1) * NSTR + n] = (unsigned)f2bf(A2) | ((unsigned)f2bf(A3) << 16);
  }
  __syncthreads();

  // fc: 8 waves. wave -> node-group g2 = wave&3 (16 nodes), out-group o = wave>>2 (4 nt)
  const int g2 = wave & 3;
  const int o = wave >> 2;
  const int l15 = lane & 15;
  const int quad = lane >> 4;
  const int node0 = nb + g2 * 16;

  int anode = node0 + l15;
  if (anode >= N_NODES) anode = N_NODES - 1;   // clamp; stores guarded
  const unsigned short* hx = xb + (size_t)anode * DFEAT;

  bf16x8 fa0 = *(const bf16x8*)(hx + quad * 8);        // k 0..31
  bf16x8 fa1 = *(const bf16x8*)(hx + 32 + quad * 8);   // k 32..63
  bf16x8 fa2, fa3;                                     // k 64..127 from ns_u
  {
    int m = g2 * 16 + l15;
    union { unsigned u[4]; bf16x8 v; } c2, c3;
#pragma unroll
    for (int i = 0; i < 4; ++i) {
      c2.u[i] = ns_u[(quad * 4 + i) * NSTR + m];
      c3.u[i] = ns_u[(16 + quad * 4 + i) * NSTR + m];
    }
    fa2 = c2.v;
    fa3 = c3.v;
  }

  f32x4 accr[4];
#pragma unroll
  for (int t = 0; t < 4; ++t) accr[t] = (f32x4){0.f, 0.f, 0.f, 0.f};

#pragma unroll
  for (int t = 0; t < 4; ++t) {
    int nt = o * 4 + t;
    const unsigned short* wr = Wb + (size_t)(nt * 16 + l15) * (2 * DFEAT) + quad * 8;
    bf16x8 b0 = *(const bf16x8*)(wr);
    bf16x8 b1 = *(const bf16x8*)(wr + 32);
    bf16x8 b2 = *(const bf16x8*)(wr + 64);
    bf16x8 b3 = *(const bf16x8*)(wr + 96);
    accr[t] = __builtin_amdgcn_mfma_f32_16x16x32_bf16(fa0, b0, accr[t], 0, 0, 0);
    accr[t] = __builtin_amdgcn_mfma_f32_16x16x32_bf16(fa1, b1, accr[t], 0, 0, 0);
    accr[t] = __builtin_amdgcn_mfma_f32_16x16x32_bf16(fa2, b2, accr[t], 0, 0, 0);
    accr[t] = __builtin_amdgcn_mfma_f32_16x16x32_bf16(fa3, b3, accr[t], 0, 0, 0);
  }

  // epilogue: D[m=quad*4+r][n=nt*16+l15]
#pragma unroll
  for (int t = 0; t < 4; ++t) {
    int nt = o * 4 + t;
    float bias = bv[nt * 16 + l15];
#pragma unroll
    for (int r = 0; r < 4; ++r) {
      int node = node0 + quad * 4 + r;
      if (node < N_NODES) {
        float v = accr[t][r] + bias;
        out[(size_t)node * HID + nt * 16 + l15] = v > 0.f ? v : 0.f;
      }
    }
  }
}

extern "C" void kernel_launch(void* const* d_in, const int* in_sizes, int n_in,
                              void* d_out, int out_size, void* d_ws, size_t ws_size,
                              hipStream_t stream) {
  const float* x = (const float*)d_in[0];
  const int* ei = (const int*)d_in[1];
  const float* W = (const float*)d_in[2];
  const float* b = (const float*)d_in[3];
  float* out = (float*)d_out;

  // workspace layout (~11 MB), 256B-aligned
  char* ws = (char*)d_ws;
  unsigned int* gbuf = (unsigned int*)ws;     ws += (size_t)NBKT * CAP_B * 4;
  unsigned short* xb = (unsigned short*)ws;   ws += (size_t)N_NODES * DFEAT * 2;
  unsigned short* Wb = (unsigned short*)ws;   ws += (size_t)HID * 2 * DFEAT * 2;
  int* bcnt = (int*)ws;                       ws += (size_t)NBKT * 4 + 192;

  hipMemsetAsync(bcnt, 0, NBKT * sizeof(int), stream);
  k_prep<<<XB2 + WB2 + EB2, 512, 0, stream>>>(x, W, ei, xb, Wb, gbuf, bcnt);
  k_gnn<<<NBKT, 512, 0, stream>>>(xb, Wb, gbuf, bcnt, b, out);
}

// Round 5
// 128.152 us; speedup vs baseline: 1.0219x; 1.0036x over previous
//
#include <hip/hip_runtime.h>

#define N_NODES 50000
#define N_EDGES 800000
#define DFEAT 64
#define HID 128
#define NBKT 782          // buckets of 64 nodes: bkt = dst>>6
#define NSEG 196          // edge blocks (4096 edges each); seg = block
#define SEGW 32           // words/segment: [count][31 entries] = 128B
#define CAP 1400          // per-bucket sorted queue: mean 1024, sigma 32 -> +11 sd
#define NSTR 66           // ns_u stride: write 2-way, frag read 2-way (free)

#define XB2 1563          // ceil(800000/512) x->bf16 blocks (512 thr)
#define WB2 8             // 4096/512 W->bf16 blocks
#define EB2 196           // edge blocks (4096 edges each)

typedef __bf16 bf16x8 __attribute__((ext_vector_type(8)));
typedef float f32x4 __attribute__((ext_vector_type(4)));

__device__ inline unsigned short f2bf(float f) {   // round-to-nearest-even
  unsigned u = __float_as_uint(f);
  return (unsigned short)((u + 0x7FFFu + ((u >> 16) & 1u)) >> 16);
}
__device__ inline float bf2f(unsigned short h) {
  return __uint_as_float(((unsigned)h) << 16);
}

// ---------- prep: bf16 cvt (x,W) + direct 64-node binning, count-embedded segs ----------
__global__ __launch_bounds__(512) void k_prep(const float* __restrict__ x,
                                              const float* __restrict__ W,
                                              const int* __restrict__ ei,
                                              unsigned short* __restrict__ xb,
                                              unsigned short* __restrict__ Wb,
                                              unsigned int* __restrict__ coarse) {
  int bid = blockIdx.x;
  const int tid = threadIdx.x;
  if (bid < XB2) {                            // x -> bf16
    int t = bid * 512 + tid;
    if (t < N_NODES * DFEAT / 4) {
      float4 v = *(const float4*)&x[t * 4];
      ushort4 o = {f2bf(v.x), f2bf(v.y), f2bf(v.z), f2bf(v.w)};
      *(ushort4*)&xb[t * 4] = o;
    }
    return;
  }
  bid -= XB2;
  if (bid < WB2) {                            // W -> bf16
    int t = bid * 512 + tid;
    float4 v = *(const float4*)&W[t * 4];
    ushort4 o = {f2bf(v.x), f2bf(v.y), f2bf(v.z), f2bf(v.w)};
    *(ushort4*)&Wb[t * 4] = o;
    return;
  }
  bid -= WB2;                                 // edge block = segment bid, 4096 edges
  __shared__ int lcnt[NBKT];
  for (int i = tid; i < NBKT; i += 512) lcnt[i] = 0;
  __syncthreads();

  int e0 = (bid * 512 + tid) * 8;
  if (e0 < N_EDGES) {                         // N_EDGES%8==0: all-or-nothing
    int4 sa = *(const int4*)&ei[e0];
    int4 sb = *(const int4*)&ei[e0 + 4];
    int4 da = *(const int4*)&ei[N_EDGES + e0];
    int4 db = *(const int4*)&ei[N_EDGES + e0 + 4];
    int ss[8] = {sa.x, sa.y, sa.z, sa.w, sb.x, sb.y, sb.z, sb.w};
    int dd[8] = {da.x, da.y, da.z, da.w, db.x, db.y, db.z, db.w};
#pragma unroll
    for (int i = 0; i < 8; ++i) {
      int bkt = dd[i] >> 6;                   // 64-node bucket, no division
      int rank = atomicAdd(&lcnt[bkt], 1);
      if (rank < SEGW - 1)
        coarse[(size_t)bkt * (NSEG * SEGW) + bid * SEGW + 1 + rank] =
            ((unsigned)dd[i] << 16) | (unsigned)ss[i];
    }
  }
  __syncthreads();
  for (int i = tid; i < NBKT; i += 512) {     // embedded count word
    int c = lcnt[i];
    coarse[(size_t)i * (NSEG * SEGW) + bid * SEGW] =
        (unsigned)(c < SEGW - 1 ? c : SEGW - 1);
  }
}

// ---------- fused: LDS-stage bucket -> in-place rank-embed sort -> edge-par gather -> MFMA fc ----------
__global__ __launch_bounds__(512) void k_gnn(const unsigned short* __restrict__ xb,
                                             const unsigned short* __restrict__ Wb,
                                             const unsigned int* __restrict__ coarse,
                                             const float* __restrict__ bv,
                                             float* __restrict__ out) {
  __shared__ unsigned int stg[NSEG * SEGW];  // 25088B staged bucket slice
  __shared__ unsigned int sq[CAP];
  __shared__ unsigned int ns_u[32 * NSTR];   // [feat-pair][node], bf16x2 packed
  __shared__ int lcnt[64];
  __shared__ int lbase[65];

  const int tid = threadIdx.x;
  const int b = blockIdx.x;
  const int nb = b * 64;
  const unsigned int* base = coarse + (size_t)b * (NSEG * SEGW);

  if (tid < 64) lcnt[tid] = 0;
  // stage the whole slice into LDS, coalesced (no atomics, read once)
  const int NU4 = NSEG * SEGW / 4;           // 1568 uint4
  for (int i = tid; i < NU4; i += 512)
    ((uint4*)stg)[i] = ((const uint4*)base)[i];
  __syncthreads();

  // rank-embed: thread s owns segment s; entry <- entry | rank<<22
  for (int s = tid; s < NSEG; s += 512) {
    int cs = (int)stg[s * SEGW];
    if (cs > SEGW - 1) cs = SEGW - 1;
    for (int k = 0; k < cs; ++k) {
      unsigned e = stg[s * SEGW + 1 + k] & 0x003fffffu;
      int rel = (int)(e >> 16);
      int rank = atomicAdd(&lcnt[rel], 1);
      stg[s * SEGW + 1 + k] = e | ((unsigned)rank << 22);
    }
  }
  __syncthreads();
  if (tid < 64) {
    int v = lcnt[tid];
    int inc = v;
#pragma unroll
    for (int o = 1; o < 64; o <<= 1) {
      int u = __shfl_up(inc, o);
      if (tid >= o) inc += u;
    }
    int ex = inc - v;
    lbase[tid] = ex < CAP ? ex : CAP;
    if (tid == 63) lbase[64] = inc < CAP ? inc : CAP;
  }
  __syncthreads();
  // scatter to sorted queue
  for (int s = tid; s < NSEG; s += 512) {
    int cs = (int)stg[s * SEGW];
    if (cs > SEGW - 1) cs = SEGW - 1;
    for (int k = 0; k < cs; ++k) {
      unsigned w = stg[s * SEGW + 1 + k];
      unsigned e = w & 0x003fffffu;
      int p = lbase[e >> 16] + (int)(w >> 22);
      if (p < CAP) sq[p] = e;
    }
  }
  __syncthreads();

  // gather: edge-parallel, zero cross-lane reduces.
  // wave (8) x lane-group g3 (4) -> 2 nodes sequentially; lane c owns feats 4c..4c+3.
  const int wave = tid >> 6;
  const int lane = tid & 63;
  const int g3 = lane >> 4;
  const int c = lane & 15;
  const uint2* xu2 = (const uint2*)xb;

#pragma unroll
  for (int i2 = 0; i2 < 2; ++i2) {
    int n = (wave * 4 + g3) * 2 + i2;
    int beg = lbase[n], end = lbase[n + 1];
    float A0 = 0.f, A1 = 0.f, A2 = 0.f, A3 = 0.f;
    float B0 = 0.f, B1 = 0.f, B2 = 0.f, B3 = 0.f;
    float C0 = 0.f, C1 = 0.f, C2 = 0.f, C3 = 0.f;
    float D0 = 0.f, D1 = 0.f, D2 = 0.f, D3 = 0.f;
    int j = beg;
    for (; j + 3 < end; j += 4) {            // ILP-4: 4 independent gathers in flight
      unsigned e0 = sq[j], e1 = sq[j + 1], e2 = sq[j + 2], e3 = sq[j + 3];
      uint2 v0 = xu2[(e0 & 0xffffu) * 16 + c];
      uint2 v1 = xu2[(e1 & 0xffffu) * 16 + c];
      uint2 v2 = xu2[(e2 & 0xffffu) * 16 + c];
      uint2 v3 = xu2[(e3 & 0xffffu) * 16 + c];
      A0 += bf2f((unsigned short)(v0.x & 0xffffu)); A1 += bf2f((unsigned short)(v0.x >> 16));
      A2 += bf2f((unsigned short)(v0.y & 0xffffu)); A3 += bf2f((unsigned short)(v0.y >> 16));
      B0 += bf2f((unsigned short)(v1.x & 0xffffu)); B1 += bf2f((unsigned short)(v1.x >> 16));
      B2 += bf2f((unsigned short)(v1.y & 0xffffu)); B3 += bf2f((unsigned short)(v1.y >> 16));
      C0 += bf2f((unsigned short)(v2.x & 0xffffu)); C1 += bf2f((unsigned short)(v2.x >> 16));
      C2 += bf2f((unsigned short)(v2.y & 0xffffu)); C3 += bf2f((unsigned short)(v2.y >> 16));
      D0 += bf2f((unsigned short)(v3.x & 0xffffu)); D1 += bf2f((unsigned short)(v3.x >> 16));
      D2 += bf2f((unsigned short)(v3.y & 0xffffu)); D3 += bf2f((unsigned short)(v3.y >> 16));
    }
    for (; j < end; ++j) {
      unsigned e = sq[j];
      uint2 v = xu2[(e & 0xffffu) * 16 + c];
      A0 += bf2f((unsigned short)(v.x & 0xffffu)); A1 += bf2f((unsigned short)(v.x >> 16));
      A2 += bf2f((unsigned short)(v.y & 0xffffu)); A3 += bf2f((unsigned short)(v.y >> 16));
    }
    A0 += B0 + C0 + D0; A1 += B1 + C1 + D1;
    A2 += B2 + C2 + D2; A3 += B3 + C3 + D3;
    ns_u[(2 * c) * NSTR + n] = (unsigned)f2bf(A0) | ((unsigned)f2bf(A1) << 16);
    ns_u[(2 * c + 1) * NSTR + n] = (unsigned)f2bf(A2) | ((unsigned)f2bf(A3) << 16);
  }
  __syncthreads();

  // fc: 8 waves. wave -> node-group g2 = wave&3 (16 nodes), out-group o = wave>>2 (4 nt)
  const int g2 = wave & 3;
  const int o = wave >> 2;
  const int l15 = lane & 15;
  const int quad = lane >> 4;
  const int node0 = nb + g2 * 16;

  int anode = node0 + l15;
  if (anode >= N_NODES) anode = N_NODES - 1;   // clamp; stores guarded
  const unsigned short* hx = xb + (size_t)anode * DFEAT;

  bf16x8 fa0 = *(const bf16x8*)(hx + quad * 8);        // k 0..31
  bf16x8 fa1 = *(const bf16x8*)(hx + 32 + quad * 8);   // k 32..63
  bf16x8 fa2, fa3;                                     // k 64..127 from ns_u
  {
    int m = g2 * 16 + l15;
    union { unsigned u[4]; bf16x8 v; } c2, c3;
#pragma unroll
    for (int i = 0; i < 4; ++i) {
      c2.u[i] = ns_u[(quad * 4 + i) * NSTR + m];
      c3.u[i] = ns_u[(16 + quad * 4 + i) * NSTR + m];
    }
    fa2 = c2.v;
    fa3 = c3.v;
  }

  f32x4 accr[4];
#pragma unroll
  for (int t = 0; t < 4; ++t) accr[t] = (f32x4){0.f, 0.f, 0.f, 0.f};

#pragma unroll
  for (int t = 0; t < 4; ++t) {
    int nt = o * 4 + t;
    const unsigned short* wr = Wb + (size_t)(nt * 16 + l15) * (2 * DFEAT) + quad * 8;
    bf16x8 b0 = *(const bf16x8*)(wr);
    bf16x8 b1 = *(const bf16x8*)(wr + 32);
    bf16x8 b2 = *(const bf16x8*)(wr + 64);
    bf16x8 b3 = *(const bf16x8*)(wr + 96);
    accr[t] = __builtin_amdgcn_mfma_f32_16x16x32_bf16(fa0, b0, accr[t], 0, 0, 0);
    accr[t] = __builtin_amdgcn_mfma_f32_16x16x32_bf16(fa1, b1, accr[t], 0, 0, 0);
    accr[t] = __builtin_amdgcn_mfma_f32_16x16x32_bf16(fa2, b2, accr[t], 0, 0, 0);
    accr[t] = __builtin_amdgcn_mfma_f32_16x16x32_bf16(fa3, b3, accr[t], 0, 0, 0);
  }

  // epilogue: D[m=quad*4+r][n=nt*16+l15]
#pragma unroll
  for (int t = 0; t < 4; ++t) {
    int nt = o * 4 + t;
    float bias = bv[nt * 16 + l15];
#pragma unroll
    for (int r = 0; r < 4; ++r) {
      int node = node0 + quad * 4 + r;
      if (node < N_NODES) {
        float v = accr[t][r] + bias;
        out[(size_t)node * HID + nt * 16 + l15] = v > 0.f ? v : 0.f;
      }
    }
  }
}

extern "C" void kernel_launch(void* const* d_in, const int* in_sizes, int n_in,
                              void* d_out, int out_size, void* d_ws, size_t ws_size,
                              hipStream_t stream) {
  const float* x = (const float*)d_in[0];
  const int* ei = (const int*)d_in[1];
  const float* W = (const float*)d_in[2];
  const float* b = (const float*)d_in[3];
  float* out = (float*)d_out;

  // workspace layout (~26 MB), 256B-aligned
  char* ws = (char*)d_ws;
  unsigned int* coarse = (unsigned int*)ws;   ws += (size_t)NBKT * NSEG * SEGW * 4;
  unsigned short* xb   = (unsigned short*)ws; ws += (size_t)N_NODES * DFEAT * 2;
  unsigned short* Wb   = (unsigned short*)ws; ws += (size_t)HID * 2 * DFEAT * 2;

  k_prep<<<XB2 + WB2 + EB2, 512, 0, stream>>>(x, W, ei, xb, Wb, coarse);
  k_gnn<<<NBKT, 512, 0, stream>>>(xb, Wb, coarse, b, out);
}